// Round 1
// baseline (985.870 us; speedup 1.0000x reference)
//
#include <hip/hip_runtime.h>

// Depth-dependent circle-of-confusion box-average, left/right views.
// B=8, C=3, H=W=1024, depth in [0,8) => R=floor(depth) in 0..7.
//
// Reference scatters each source (y,x) over rect [y-R,y+R]x[x-2R,x] (left)
// and [y-R,y+R]x[x,x+2R] (right) via integral-image corners + double cumsum.
// Since dests are always in-image and corner clamping == rect-intersect-image,
// this is exactly the gather:
//   left (Y,X): sum of sources with |Y-y|<=R and 0 <= x-X <= 2R
//   right(Y,X): sum of sources with |Y-y|<=R and 0 <= X-x <= 2R
//   cond  <=>  depth(y,x) >= max(|dy|, ceil(|dx|/2))   (t integer, exact fp cmp)
// Then out = clip(acc / max(cnt,1), 0, 1).

constexpr int Hh = 1024, Ww = 1024, Bb = 8, Cc = 3;
constexpr int RMAX = 7;              // depth < 8.0 (jax uniform [0,8))
constexpr int TW = 64, TH = 16, LJ = 4;   // dest tile 64x16, 4 Y-dests/thread
constexpr int HX = 2 * RMAX;         // 14
constexpr int HY = RMAX;             // 7
constexpr int WCOLS = TW + 2 * HX;   // 92
constexpr int WROWS = TH + 2 * HY;   // 30

__global__ __launch_bounds__(256)
void coc_gather(const float* __restrict__ img, const float* __restrict__ dep,
                float* __restrict__ out) {
  __shared__ float4 tile[WROWS * WCOLS];   // (r,g,b,depth), 44160 B
  const int tx = threadIdx.x;              // 0..63  (dest X within tile)
  const int ty = threadIdx.y;              // 0..3   (dest Y group)
  const int tid = ty * 64 + tx;
  const int X0 = blockIdx.x * TW;
  const int Y0 = blockIdx.y * TH;
  const int b  = blockIdx.z;
  const size_t plane = (size_t)Hh * Ww;

  const float* db = dep + (size_t)b * plane;
  const float* ib = img + (size_t)b * Cc * plane;

  // ---- stage source window into LDS (OOB -> depth sentinel -1, never fires)
  for (int idx = tid; idx < WROWS * WCOLS; idx += 256) {
    int lr = idx / WCOLS;
    int lc = idx - lr * WCOLS;
    int gy = Y0 - HY + lr;
    int gx = X0 - HX + lc;
    float4 v = make_float4(0.f, 0.f, 0.f, -1.f);
    if ((unsigned)gy < (unsigned)Hh && (unsigned)gx < (unsigned)Ww) {
      size_t p = (size_t)gy * Ww + gx;
      v.x = ib[p];
      v.y = ib[plane + p];
      v.z = ib[2 * plane + p];
      v.w = db[p];
    }
    tile[idx] = v;
  }
  __syncthreads();

  float4 aL[LJ], aR[LJ];   // (cnt, r, g, b) accumulators per dest row
  #pragma unroll
  for (int j = 0; j < LJ; ++j) {
    aL[j] = make_float4(0.f, 0.f, 0.f, 0.f);
    aR[j] = make_float4(0.f, 0.f, 0.f, 0.f);
  }

  const int lbase = ty * LJ;   // this thread's dest rows: Y0 + lbase + j
  #pragma unroll 1
  for (int sy = 0; sy < LJ + 2 * HY; ++sy) {          // 18 source rows
    // source row (global) = Y0 + lbase + sy - HY ; dy for dest j = sy - HY - j
    const float4* row = &tile[(lbase + sy) * WCOLS + tx + HX];  // dx = 0
    #pragma unroll 1
    for (int adx = 0; adx <= HX; ++adx) {             // 15, mirrored views
      const float4 sL = row[adx];    // left-view candidate  (dx = +adx)
      const float4 sR = row[-adx];   // right-view candidate (dx = -adx)
      const float hdxf = (float)((adx + 1) >> 1);
      #pragma unroll
      for (int j = 0; j < LJ; ++j) {
        int dy = sy - HY - j;
        int ady = dy < 0 ? -dy : dy;
        float tf = fmaxf((float)ady, hdxf);
        float wL = (sL.w >= tf) ? 1.0f : 0.0f;
        float wR = (sR.w >= tf) ? 1.0f : 0.0f;
        aL[j].x += wL;         aR[j].x += wR;
        aL[j].y += wL * sL.x;  aR[j].y += wR * sR.x;
        aL[j].z += wL * sL.y;  aR[j].z += wR * sR.y;
        aL[j].w += wL * sL.z;  aR[j].w += wR * sR.z;
      }
    }
  }
  // note: adx=0 (the dest's own column) legitimately belongs to BOTH views.

  float* outL = out + (size_t)b * Cc * plane;               // left block
  float* outR = out + (size_t)(Bb + b) * Cc * plane;        // right block
  #pragma unroll
  for (int j = 0; j < LJ; ++j) {
    int Y = Y0 + lbase + j;
    size_t p = (size_t)Y * Ww + (X0 + tx);
    float invL = 1.0f / fmaxf(aL[j].x, 1.0f);
    float invR = 1.0f / fmaxf(aR[j].x, 1.0f);
    outL[p]             = fminf(fmaxf(aL[j].y * invL, 0.f), 1.f);
    outL[plane + p]     = fminf(fmaxf(aL[j].z * invL, 0.f), 1.f);
    outL[2 * plane + p] = fminf(fmaxf(aL[j].w * invL, 0.f), 1.f);
    outR[p]             = fminf(fmaxf(aR[j].y * invR, 0.f), 1.f);
    outR[plane + p]     = fminf(fmaxf(aR[j].z * invR, 0.f), 1.f);
    outR[2 * plane + p] = fminf(fmaxf(aR[j].w * invR, 0.f), 1.f);
  }
}

extern "C" void kernel_launch(void* const* d_in, const int* in_sizes, int n_in,
                              void* d_out, int out_size, void* d_ws, size_t ws_size,
                              hipStream_t stream) {
  const float* img = (const float*)d_in[0];   // (8,3,1024,1024) f32
  const float* dep = (const float*)d_in[1];   // (8,1024,1024) f32
  float* out = (float*)d_out;                 // left then right, each (8,3,1024,1024)
  dim3 grid(Ww / TW, Hh / TH, Bb);            // 16 x 64 x 8 = 8192 blocks
  dim3 block(64, 4, 1);
  hipLaunchKernelGGL(coc_gather, grid, block, 0, stream, img, dep, out);
}

// Round 2
// 796.654 us; speedup vs baseline: 1.2375x; 1.2375x over previous
//
#include <hip/hip_runtime.h>

// Depth-dependent circle-of-confusion box-average, left/right views.
// Gather form: dest (Y,X) left view sums sources with |Y-y|<=R, 0<=x-X<=2R,
// where R = floor(depth) in 0..7. Condition is separable:
//   [R >= max(ady,hdx)] = [R>=hdx]*[R>=ady],  hdx = ceil(|dx|/2)
// and for integer-valued floats  [R >= t] == saturate(R - t + 1)  (1 VALU op).
// The hdx factor is hoisted across the 4 register-blocked dest rows.

constexpr int Hh = 1024, Ww = 1024, Bb = 8, Cc = 3;
constexpr int RMAX = 7;                   // depth in [0,8)
constexpr int TW = 64, TH = 16, LJ = 4;   // dest tile 64x16, 4 Y-dests/thread
constexpr int HX = 2 * RMAX;              // 14
constexpr int HY = RMAX;                  // 7
constexpr int WCOLS = TW + 2 * HX;        // 92
constexpr int WROWS = TH + 2 * HY;        // 30

__device__ __forceinline__ float sat01(float x) {
  return fminf(fmaxf(x, 0.0f), 1.0f);     // folds to v_add clamp / v_med3
}

__global__ __launch_bounds__(256)
void coc_gather(const float* __restrict__ img, const float* __restrict__ dep,
                float* __restrict__ out) {
  __shared__ float4 tile[WROWS * WCOLS];  // (r,g,b,R) ; R=floor(depth), 44160 B
  const int tx = threadIdx.x;             // 0..63 (dest X within tile)
  const int ty = threadIdx.y;             // 0..3
  const int tid = ty * 64 + tx;
  const int X0 = blockIdx.x * TW;
  const int Y0 = blockIdx.y * TH;
  const int b  = blockIdx.z;
  const size_t plane = (size_t)Hh * Ww;

  const float* db = dep + (size_t)b * plane;
  const float* ib = img + (size_t)b * Cc * plane;

  // ---- stage source window; OOB sentinel R=-1 makes all weights 0
  for (int idx = tid; idx < WROWS * WCOLS; idx += 256) {
    int lr = idx / WCOLS;
    int lc = idx - lr * WCOLS;
    int gy = Y0 - HY + lr;
    int gx = X0 - HX + lc;
    float4 v = make_float4(0.f, 0.f, 0.f, -1.f);
    if ((unsigned)gy < (unsigned)Hh && (unsigned)gx < (unsigned)Ww) {
      size_t p = (size_t)gy * Ww + gx;
      v.x = ib[p];
      v.y = ib[plane + p];
      v.z = ib[2 * plane + p];
      v.w = floorf(db[p]);                // pre-floor: integer-valued R
    }
    tile[idx] = v;
  }
  __syncthreads();

  float4 aL[LJ], aR[LJ];                  // (cnt, r, g, b) per dest row
  #pragma unroll
  for (int j = 0; j < LJ; ++j) {
    aL[j] = make_float4(0.f, 0.f, 0.f, 0.f);
    aR[j] = make_float4(0.f, 0.f, 0.f, 0.f);
  }

  const int lbase = ty * LJ;              // dest rows: Y0 + lbase + j
  #pragma unroll 1
  for (int sy = 0; sy < LJ + 2 * HY; ++sy) {        // 18 source rows
    const float4* row = &tile[(lbase + sy) * WCOLS + tx + HX];  // dx = 0
    // wave-uniform per-j threshold constants: cj = 1 - |dy|
    float cj[LJ];
    #pragma unroll
    for (int j = 0; j < LJ; ++j) {
      int dy = sy - HY - j;
      int ady = dy < 0 ? -dy : dy;
      cj[j] = 1.0f - (float)ady;
    }
    #pragma unroll
    for (int adx = 0; adx <= HX; ++adx) {           // 15 taps, mirrored views
      const float chd = (float)(1 - ((adx + 1) >> 1));   // 1 - hdx, compile-time
      const float4 sL = row[adx];     // left view  (dx = +adx)
      const float4 sR = row[-adx];    // right view (dx = -adx)
      // hoisted hdx-side weight, pre-multiplied into values (shared by 4 j's)
      const float whL = sat01(sL.w + chd);
      const float whR = sat01(sR.w + chd);
      const float4 vL = make_float4(whL, whL * sL.x, whL * sL.y, whL * sL.z);
      const float4 vR = make_float4(whR, whR * sR.x, whR * sR.y, whR * sR.z);
      #pragma unroll
      for (int j = 0; j < LJ; ++j) {
        const float waL = sat01(sL.w + cj[j]);      // [R >= ady]
        const float waR = sat01(sR.w + cj[j]);
        aL[j].x = fmaf(waL, vL.x, aL[j].x);
        aL[j].y = fmaf(waL, vL.y, aL[j].y);
        aL[j].z = fmaf(waL, vL.z, aL[j].z);
        aL[j].w = fmaf(waL, vL.w, aL[j].w);
        aR[j].x = fmaf(waR, vR.x, aR[j].x);
        aR[j].y = fmaf(waR, vR.y, aR[j].y);
        aR[j].z = fmaf(waR, vR.z, aR[j].z);
        aR[j].w = fmaf(waR, vR.w, aR[j].w);
      }
    }
  }

  float* outL = out + (size_t)b * Cc * plane;
  float* outR = out + (size_t)(Bb + b) * Cc * plane;
  #pragma unroll
  for (int j = 0; j < LJ; ++j) {
    int Y = Y0 + lbase + j;
    size_t p = (size_t)Y * Ww + (X0 + tx);
    float invL = 1.0f / fmaxf(aL[j].x, 1.0f);
    float invR = 1.0f / fmaxf(aR[j].x, 1.0f);
    outL[p]             = fminf(fmaxf(aL[j].y * invL, 0.f), 1.f);
    outL[plane + p]     = fminf(fmaxf(aL[j].z * invL, 0.f), 1.f);
    outL[2 * plane + p] = fminf(fmaxf(aL[j].w * invL, 0.f), 1.f);
    outR[p]             = fminf(fmaxf(aR[j].y * invR, 0.f), 1.f);
    outR[plane + p]     = fminf(fmaxf(aR[j].z * invR, 0.f), 1.f);
    outR[2 * plane + p] = fminf(fmaxf(aR[j].w * invR, 0.f), 1.f);
  }
}

extern "C" void kernel_launch(void* const* d_in, const int* in_sizes, int n_in,
                              void* d_out, int out_size, void* d_ws, size_t ws_size,
                              hipStream_t stream) {
  const float* img = (const float*)d_in[0];   // (8,3,1024,1024) f32
  const float* dep = (const float*)d_in[1];   // (8,1024,1024) f32
  float* out = (float*)d_out;                 // left then right
  dim3 grid(Ww / TW, Hh / TH, Bb);            // 8192 blocks
  dim3 block(64, 4, 1);
  hipLaunchKernelGGL(coc_gather, grid, block, 0, stream, img, dep, out);
}